// Round 21
// baseline (431.921 us; speedup 1.0000x reference)
//
#include <hip/hip_runtime.h>

// B=2, T=12, C=128, H=W=32, heads=4, dh=32, layers=5. fp32 I/O.
// Algebra: key-axis softmax cancels q-conv & att_b; attention weights are
// query-independent (head output broadcast over the 12 frames).
// Round 21: base = R20 (best, 428.0us). Same win-class (structural read cut):
// kv-conv waves now own ADJACENT rows (w0:0-2, w1:3-5, w2:6-8, w3:9) so one
// staged-row ds_read feeds up to 3 MFMAs (fi = ari-ky, static acc index),
// exactly the ff1/R9 A-reuse trick. Block reads 180 -> 108 (-40%), MFMA
// count and per-wave critical path unchanged. Guards wave-uniform; acc
// indices compile-time. VGPR ~150 < 256 cap; occupancy LDS-bound unchanged.
#define NELEM 3145728
#define IMG 24
#define CH 128
#define HW 1024

using short8   = __attribute__((ext_vector_type(8))) short;
using ushort4v = __attribute__((ext_vector_type(4))) unsigned short;
using float4v  = __attribute__((ext_vector_type(4))) float;
using float16v = __attribute__((ext_vector_type(16))) float;

__device__ inline unsigned short f2bf(float f){
    union { float f; unsigned u; } c; c.f = f;
    return (unsigned short)((c.u + 0x7FFF + ((c.u >> 16) & 1)) >> 16);
}

// ---------------- fused prep: weight transforms + input transpose ----------------
// Dense W3 layout: short8 idx = ((tap*8 + k16)*2 + kh)*128 + co ; j=ci%8,
// ci = k16*16 + kh*8 + j. KV W3: short8 idx = ((tap*2 + k16)*2 + kh)*128 + co,
// ci_local = k16*16 + kh*8 + j (head = co>>5).
__global__ __launch_bounds__(256) void k_prep(
    const float* __restrict__ ff1w, const float* __restrict__ ff2w,
    const float* __restrict__ kvw, const float* __restrict__ input,
    unsigned short* __restrict__ Wd, unsigned short* __restrict__ Wkv,
    float* __restrict__ cur)
{
    const int t = threadIdx.x;
    __shared__ float tile[32 * 132];
    if (blockIdx.x < 5760) {
        int idx = blockIdx.x * 256 + t;
        int li2 = idx / 147456, r1 = idx - li2 * 147456;
        int j = r1 & 7, co = (r1 >> 3) & 127;
        int kh = (r1 >> 10) & 1, k16 = (r1 >> 11) & 7, tap = r1 >> 14;
        int ci = k16 * 16 + kh * 8 + j;
        const float* base = ((li2 & 1) ? ff2w : ff1w) + (size_t)(li2 >> 1) * 147456;
        Wd[idx] = f2bf(base[(co * 128 + ci) * 9 + tap]);
    } else if (blockIdx.x < 6480) {
        int idx = (blockIdx.x - 5760) * 256 + t;
        int li = idx / 36864, r1 = idx - li * 36864;
        int j = r1 & 7, co = (r1 >> 3) & 127;
        int kh = (r1 >> 10) & 1, k16 = (r1 >> 11) & 1, tap = r1 >> 12;
        int h = co >> 5, colc = co & 31, cil = k16 * 16 + kh * 8 + j;
        Wkv[idx] = f2bf(kvw[((size_t)((li * 4 + h) * 32 + colc) * 32 + cil) * 9 + tap]);
    } else {
        int bb = blockIdx.x - 6480;                  // 24 img x 32 px-tiles
        int img = bb >> 5, px0 = (bb & 31) * 32;
        #pragma unroll
        for (int it = 0; it < 4; it++) {
            int c = it * 32 + (t >> 3), pxq = t & 7;
            float4v val = *(const float4v*)(input + ((size_t)img * 128 + c) * HW + px0 + pxq * 4);
            #pragma unroll
            for (int j = 0; j < 4; j++) tile[(pxq * 4 + j) * 132 + c] = val[j];
        }
        __syncthreads();
        #pragma unroll
        for (int it = 0; it < 4; it++) {
            int px = it * 8 + (t >> 5), cq = t & 31;
            float4v o = *(float4v*)(tile + px * 132 + cq * 4);
            *(float4v*)(cur + ((size_t)img * HW + px0 + px) * 128 + cq * 4) = o;
        }
    }
}

// ---------------- fused kv-conv + attention-logit conv ----------------
// kv-conv (R21): wave w owns adjacent rows (w0:0-2, w1:3-5, w2:6-8, w3:9);
// A-reuse: iterate staged rows ar = fbase+ari, one ds_read feeds up to 3
// MFMAs (fi = ari-ky static). B-fragments hoisted (R20).
// Logit conv (R19): 4 x-adjacent px/thread, ci split 4-ways across waves;
// partials -> sred (aliased over dead slab) -> 64-thread tree -> float4.
__global__ __launch_bounds__(256, 2) void k_kvattn(
    const float* __restrict__ cur, const unsigned short* __restrict__ wkv,
    const float* __restrict__ kvb, const float* __restrict__ aw,
    const float* __restrict__ pstatp, const float* __restrict__ gw,
    const float* __restrict__ gb, float* __restrict__ v,
    float* __restrict__ ak, float* __restrict__ pstatz)
{
    const int img = blockIdx.x, h = blockIdx.y, y0 = blockIdx.z * 8;
    const int t = threadIdx.x;
    const int b = img / 12, l = img - b * 12;

    if (blockIdx.x == 0 && blockIdx.y == 0 && blockIdx.z == 0 && t < 192)
        pstatz[t] = 0.f;

    __shared__ float sxv[32 * 353];                            // 45184 B
    __shared__ __align__(16) unsigned short slab[408 * 40];    // 32640 B
    __shared__ float spos[32], sbias[32], sgw[32], sgb[32];

    if (t < 32) {
        int j2 = t & ~1;
        float freq = __expf(-(float)j2 * 0.28782313662425576f);
        float ang = (float)l * freq;
        spos[t] = (t & 1) ? __cosf(ang) : __sinf(ang);
        sbias[t] = kvb[h * 32 + t];
        sgw[t] = gw ? gw[h * 32 + t] : 1.f;
        sgb[t] = gb ? gb[h * 32 + t] : 0.f;
    }
    float mu = 0.f, inv = 1.f;
    if (pstatp) {
        float S = pstatp[(img * 4 + h) * 2], Q = pstatp[(img * 4 + h) * 2 + 1];
        mu = S * (1.f / 32768.f);
        inv = rsqrtf(Q * (1.f / 32768.f) - mu * mu + 1e-5f);
    }
    __syncthreads();

    // stage: 12 rows x 34 cols x 8 float4-groups of the head's 32 ch
    for (int u = t; u < 3264; u += 256) {
        int q = u & 7, p = u >> 3;
        int lr = p / 34, lc = p - lr * 34;
        int yr = y0 - 2 + lr, x = lc - 1;
        float4v val = (float4v){0.f, 0.f, 0.f, 0.f};
        if (yr >= 0 && yr < 32 && x >= 0 && x < 32) {
            val = *(const float4v*)(cur + ((size_t)img * HW + yr * 32 + x) * 128 + h * 32 + q * 4);
            #pragma unroll
            for (int j = 0; j < 4; j++)
                val[j] = (val[j] - mu) * inv * sgw[q * 4 + j] + sgb[q * 4 + j];
        }
        ushort4v o;
        #pragma unroll
        for (int j = 0; j < 4; j++) o[j] = f2bf(val[j]);
        *(ushort4v*)(slab + p * 40 + q * 4) = o;
    }
    __syncthreads();

    const int lane = t & 63, wave = t >> 6;
    const int colx = lane & 31, kh = lane >> 5;
    const short8* w8 = reinterpret_cast<const short8*>(wkv);

    // hoisted f-invariant B fragments: 18 short8 (72 VGPR)
    short8 BV[9][2];
    #pragma unroll
    for (int tap = 0; tap < 9; tap++)
        #pragma unroll
        for (int k16 = 0; k16 < 2; k16++)
            BV[tap][k16] = w8[((tap * 2 + k16) * 2 + kh) * 128 + h * 32 + colx];

    // kv-conv with A-reuse: wave's rows fbase..fbase+2 (wave 3: row 9 only)
    const int fbase = (wave == 3) ? 9 : wave * 3;
    float16v acc[3];
    #pragma unroll
    for (int fi = 0; fi < 3; fi++)
        #pragma unroll
        for (int r = 0; r < 16; r++) acc[fi][r] = 0.f;

    #pragma unroll
    for (int ari = 0; ari < 5; ari++) {
        if (fbase + ari < 12) {                 // staged rows 0..11 (wave-uniform)
            #pragma unroll
            for (int kx = 0; kx < 3; kx++) {
                #pragma unroll
                for (int k16 = 0; k16 < 2; k16++) {
                    short8 a = *reinterpret_cast<const short8*>(
                        slab + ((fbase + ari) * 34 + colx + kx) * 40 + k16 * 16 + kh * 8);
                    #pragma unroll
                    for (int ky = 0; ky < 3; ky++) {
                        const int fi = ari - ky;            // static acc index
                        if (fi >= 0 && fi < 3)
                            if (fbase + fi < 10)            // wave-uniform
                                acc[fi] = __builtin_amdgcn_mfma_f32_32x32x16_bf16(
                                    a, BV[ky * 3 + kx][k16], acc[fi], 0, 0, 0);
                    }
                }
            }
        }
    }

    #pragma unroll
    for (int fi = 0; fi < 3; fi++) {
        const int f = fbase + fi;
        if (f < 10) {                           // wave-uniform
            const int yr = y0 - 1 + f;
            const bool rowin = (yr >= 0 && yr < 32);
            const bool vown = rowin && f >= 1 && f <= 8;   // rows this block owns
            const float posci = spos[colx], bb = sbias[colx];
            float* vrow = v + ((size_t)img * HW + yr * 32) * 128 + h * 32 + colx;
            #pragma unroll
            for (int r = 0; r < 16; r++) {
                int x2 = (r & 3) + 8 * (r >> 2) + 4 * kh;
                float val = rowin ? acc[fi][r] + bb : 0.f;
                if (vown) vrow[(size_t)x2 * 128] = val;
                sxv[colx * 353 + f * 35 + x2 + 1] = rowin ? val + posci : 0.f;
            }
        }
    }
    // zero padded border cols (0 and 33) of all 10 rows
    for (int u = t; u < 640; u += 256) {
        int ci = u & 31, r2 = u >> 5;
        sxv[ci * 353 + (r2 >> 1) * 35 + ((r2 & 1) ? 33 : 0)] = 0.f;
    }
    __syncthreads();

    // logit conv: thread (g=wave, u=lane) computes 4 px (row rr, cols x0..x0+3)
    // over its 8-ci octet: 6-float row windows feed 12 fmaf each (ky).
    const int g = wave, u2 = lane;
    const int rr = u2 >> 3, x0 = (u2 & 7) * 4;
    const float* wbg = aw + (h * 64 + 32) * 9 + g * 72;   // K-half, ci octet g
    float4v pacc = (float4v){0.f, 0.f, 0.f, 0.f};
    #pragma unroll
    for (int ci = 0; ci < 8; ci++) {
        const float* sp = sxv + (g * 8 + ci) * 353 + rr * 35 + x0;
        const float* wp = wbg + ci * 9;
        #pragma unroll
        for (int ky = 0; ky < 3; ky++) {
            float f0 = sp[ky*35+0], f1 = sp[ky*35+1], f2 = sp[ky*35+2];
            float f3 = sp[ky*35+3], f4 = sp[ky*35+4], f5 = sp[ky*35+5];
            float w0 = wp[ky*3+0], w1 = wp[ky*3+1], w2f = wp[ky*3+2];
            pacc[0] = fmaf(f2, w2f, fmaf(f1, w1, fmaf(f0, w0, pacc[0])));
            pacc[1] = fmaf(f3, w2f, fmaf(f2, w1, fmaf(f1, w0, pacc[1])));
            pacc[2] = fmaf(f4, w2f, fmaf(f3, w1, fmaf(f2, w0, pacc[2])));
            pacc[3] = fmaf(f5, w2f, fmaf(f4, w1, fmaf(f3, w0, pacc[3])));
        }
    }
    // reduce across the 4 ci-octets via LDS (sred aliased over dead slab)
    float4v* sred = reinterpret_cast<float4v*>(slab);
    sred[g * 64 + u2] = pacc;
    __syncthreads();
    if (t < 64) {
        float4v s = sred[t];
        #pragma unroll
        for (int gg = 1; gg < 4; gg++) {
            float4v o = sred[gg * 64 + t];
            #pragma unroll
            for (int j = 0; j < 4; j++) s[j] += o[j];
        }
        *reinterpret_cast<float4v*>(ak + ((size_t)(b * 4 + h) * 12 + l) * HW
                                    + (y0 + (t >> 3)) * 32 + (t & 7) * 4) = s;
    }
}

// ---------------- fused FFN: cout = conv(relu(conv(cin,ff1)+b1),ff2)+b2+cin ----------------
// grid (24 img, 32 y). Block 256 = 4 waves, wave w owns co group w*32..+32.
// LDS aliased (46240 B, 3 blocks/CU):
//   phase A: s1 = 5 padded rows x 34 x 128ch bf16 of cin (stride 136).
//   phase B (after ff1's reads drain): s2 = 3 f1 rows (stride 136) at base.
// ff1 A-reuse (R9): one ds_read feeds up to 3 MFMAs. B dbuf as R11.
// Direct-from-accumulator epilogue (R13): ff2 D-frag = 2x128B contiguous
// global segments per reg; residual cin prefetched into regs after bar3;
// GN stats full-wave butterfly (group == wave id), 2 atomics/wave.
__global__ __launch_bounds__(256, 2) void k_ffn(
    const float* __restrict__ cin, const unsigned short* __restrict__ w1,
    const float* __restrict__ b1, const unsigned short* __restrict__ w2,
    const float* __restrict__ b2, float* __restrict__ cout,
    float* __restrict__ pstat)
{
    const int img = blockIdx.x, y = blockIdx.y;
    const int t = threadIdx.x;
    const int wave = t >> 6, lane = t & 63;
    const int colx = lane & 31, kh = lane >> 5;
    const int cog = wave * 32;

    __shared__ __align__(16) char smem[46240];
    unsigned short* s1 = (unsigned short*)smem;          // 170*136 shorts
    unsigned short* s2 = (unsigned short*)smem;          // 102*136 shorts (aliased)

    // stage s1: rows y-2..y+2, cols -1..32, 128 ch (border-checked)
    for (int u = t; u < 5440; u += 256) {
        int q = u & 31, p = u >> 5;
        int lr = p / 34, lc = p - lr * 34;
        int yr = y - 2 + lr, x = lc - 1;
        float4v val = (float4v){0.f, 0.f, 0.f, 0.f};
        if (yr >= 0 && yr < 32 && x >= 0 && x < 32)
            val = *(const float4v*)(cin + ((size_t)img * HW + yr * 32 + x) * 128 + q * 4);
        ushort4v o;
        #pragma unroll
        for (int j = 0; j < 4; j++) o[j] = f2bf(val[j]);
        *(ushort4v*)(s1 + p * 136 + q * 4) = o;
    }

    const short8* w8a = reinterpret_cast<const short8*>(w1);
    const short8* w8b = reinterpret_cast<const short8*>(w2);
    const int bl = kh * 128 + cog + colx;       // per-lane short8 index into W3

    float16v acc[3];
    #pragma unroll
    for (int f = 0; f < 3; f++)
        #pragma unroll
        for (int r = 0; r < 16; r++) acc[f][r] = 0.f;

    // ff1 B double buffer: prefetch k16=0's 9 taps (overlaps stage + barrier)
    short8 B9[2][9];
    #pragma unroll
    for (int tap = 0; tap < 9; tap++)
        B9[0][tap] = w8a[(tap * 8 + 0) * 256 + bl];

    __syncthreads();                            // bar1: s1 staged

    // ff1: A-reuse across output rows. For (ar,kx,k16): one ds_read feeds
    // acc[ar-ky] for all valid ky. 15 reads + 27 MFMA per k16; next k16's
    // 9 B-loads issue before the MFMA burst (latency hidden under compute).
    #pragma unroll
    for (int k16 = 0; k16 < 8; k16++) {
        if (k16 + 1 < 8) {
            #pragma unroll
            for (int tap = 0; tap < 9; tap++)
                B9[(k16 + 1) & 1][tap] = w8a[(tap * 8 + k16 + 1) * 256 + bl];
        }
        #pragma unroll
        for (int ar = 0; ar < 5; ar++) {
            #pragma unroll
            for (int kx = 0; kx < 3; kx++) {
                short8 a = *reinterpret_cast<const short8*>(
                    s1 + (ar * 34 + kx + colx) * 136 + kh * 8 + k16 * 16);
                #pragma unroll
                for (int ky = 0; ky < 3; ky++) {
                    const int f = ar - ky;
                    if (f >= 0 && f < 3)
                        acc[f] = __builtin_amdgcn_mfma_f32_32x32x16_bf16(
                            a, B9[k16 & 1][ky * 3 + kx], acc[f], 0, 0, 0);
                }
            }
        }
    }

    // ff2 B double buffer
    short8 bfr[2][8];
    auto loadB2 = [&](int tap, int buf){
        #pragma unroll
        for (int k16 = 0; k16 < 8; k16++)
            bfr[buf][k16] = w8b[(tap * 8 + k16) * 256 + bl];
    };
    loadB2(0, 0);                               // overlap with barrier + s2 writes
    __syncthreads();                            // bar2: all s1 reads done

    // write f1 rows into s2 (aliased over s1): relu + bias; zero rows outside
    {
        const int co = cog + colx;
        const float bb1 = b1[co];
        #pragma unroll
        for (int f = 0; f < 3; f++) {
            const bool rowin = (y - 1 + f >= 0) && (y - 1 + f < 32);
            #pragma unroll
            for (int r = 0; r < 16; r++) {
                int x2 = (r & 3) + 8 * (r >> 2) + 4 * kh;
                float val = rowin ? fmaxf(acc[f][r] + bb1, 0.f) : 0.f;
                s2[(f * 34 + x2 + 1) * 136 + co] = f2bf(val);
            }
        }
    }
    // zero s2 border cols (x=0 and x=33) of all 3 rows
    for (int u = t; u < 768; u += 256) {
        int c = u & 127, rr = u >> 7;            // rr 0..5
        s2[((rr >> 1) * 34 + ((rr & 1) ? 33 : 0)) * 136 + c] = 0;
    }
    __syncthreads();                            // bar3: s2 ready

    // prefetch residual cin for this wave's 16 output elements (hidden
    // under ff2's MFMAs; 2x128B contiguous segments per r across the wave)
    const int co = cog + colx;
    float res[16];
    #pragma unroll
    for (int r = 0; r < 16; r++) {
        int x2 = (r & 3) + 8 * (r >> 2) + 4 * kh;
        res[r] = cin[((size_t)img * HW + y * 32 + x2) * 128 + co];
    }

    // ff2: row y; prefetch tap+1's B under tap's MFMAs
    float16v a2;
    #pragma unroll
    for (int r = 0; r < 16; r++) a2[r] = 0.f;
    #pragma unroll
    for (int tap = 0; tap < 9; tap++) {
        if (tap + 1 < 9) loadB2(tap + 1, (tap + 1) & 1);
        const int ky = tap / 3, kx = tap - ky * 3;
        #pragma unroll
        for (int k16 = 0; k16 < 8; k16++) {
            short8 a = *reinterpret_cast<const short8*>(
                s2 + (ky * 34 + kx + colx) * 136 + kh * 8 + k16 * 16);
            a2 = __builtin_amdgcn_mfma_f32_32x32x16_bf16(a, bfr[tap & 1][k16], a2, 0, 0, 0);
        }
    }

    // direct epilogue: bias + residual + store from accumulator + GN stats
    const float bb2 = b2[co];
    float ps1 = 0.f, ps2 = 0.f;
    #pragma unroll
    for (int r = 0; r < 16; r++) {
        int x2 = (r & 3) + 8 * (r >> 2) + 4 * kh;
        float val = a2[r] + bb2 + res[r];
        cout[((size_t)img * HW + y * 32 + x2) * 128 + co] = val;
        ps1 += val; ps2 += val * val;
    }
    // all 64 lanes share channel-group == wave id: full butterfly reduce
    #pragma unroll
    for (int o = 32; o > 0; o >>= 1) {
        ps1 += __shfl_xor(ps1, o); ps2 += __shfl_xor(ps2, o);
    }
    if (lane == 0) {
        atomicAdd(&pstat[(img * 4 + wave) * 2], ps1);
        atomicAdd(&pstat[(img * 4 + wave) * 2 + 1], ps2);
    }
}

// ---------------- fused softmax + weighted sum + GN-on-read residual ----------------
// one channel per thread: 262144 threads, 1024 blocks (4/CU), all coalesced.
__global__ __launch_bounds__(256) void k_wsum(const float* __restrict__ ak,
    const float* __restrict__ v, float* __restrict__ cur,
    const float* __restrict__ pstatp, const float* __restrict__ gw,
    const float* __restrict__ gb)
{
    int gid = blockIdx.x * 256 + threadIdx.x;   // 2*1024*128
    int c = gid & 127, px = (gid >> 7) & 1023, b = gid >> 17;
    int h = c >> 5;
    const float* wp = ak + ((size_t)(b * 4 + h) * 12) * HW + px;
    float a[12], m = -1e30f;
    #pragma unroll
    for (int l = 0; l < 12; l++) { a[l] = wp[l * HW]; m = fmaxf(m, a[l]); }
    float ssum = 0.f;
    #pragma unroll
    for (int l = 0; l < 12; l++) { a[l] = __expf(a[l] - m); ssum += a[l]; }
    float invs = 1.f / ssum;
    const float* vp = v + ((size_t)(b * 12) * HW + px) * 128 + c;
    float s = 0.f;
    #pragma unroll
    for (int l = 0; l < 12; l++) s += a[l] * vp[(size_t)l * HW * 128];
    s *= invs;
    float gwv = gw ? gw[c] : 1.f, gbv = gb ? gb[c] : 0.f;
    float* cp = cur + ((size_t)(b * 12) * HW + px) * 128 + c;
    #pragma unroll
    for (int l = 0; l < 12; l++) {
        int img = b * 12 + l;
        float mu = 0.f, inv = 1.f;
        if (pstatp) {
            float S = pstatp[(img * 4 + h) * 2], Q = pstatp[(img * 4 + h) * 2 + 1];
            mu = S * (1.f / 32768.f);
            inv = rsqrtf(Q * (1.f / 32768.f) - mu * mu + 1e-5f);
        }
        float cv = cp[(size_t)l * HW * 128];
        cp[(size_t)l * HW * 128] = (cv - mu) * inv * gwv + gbv + s;
    }
}

// ---------------- final GroupNorm + NCHW transpose ----------------
__global__ __launch_bounds__(256) void k_gnlast(const float* __restrict__ y,
    const float* __restrict__ pstat, const float* __restrict__ gw,
    const float* __restrict__ gb, float* __restrict__ outp)
{
    int gid = blockIdx.x * 256 + threadIdx.x;   // 24*1024*32
    int px4 = (gid & 255) * 4, c = (gid >> 8) & 127, img = gid >> 15;
    int g = c >> 5;
    float S = pstat[(img * 4 + g) * 2], Q = pstat[(img * 4 + g) * 2 + 1];
    float mu = S * (1.f / 32768.f);
    float inv = rsqrtf(Q * (1.f / 32768.f) - mu * mu + 1e-5f);
    float gg = gw[c], bb = gb[c];
    float4v o;
    #pragma unroll
    for (int j = 0; j < 4; j++) {
        float val = y[((size_t)img * HW + px4 + j) * 128 + c];
        o[j] = (val - mu) * inv * gg + bb;
    }
    *(float4v*)(outp + ((size_t)img * 128 + c) * HW + px4) = o;
}

extern "C" void kernel_launch(void* const* d_in, const int* in_sizes, int n_in,
                              void* d_out, int out_size, void* d_ws, size_t ws_size,
                              hipStream_t stream)
{
    const float* input = (const float*)d_in[0];
    // d_in[1] q_w, d_in[2] q_b, d_in[6] att_b cancel in key-axis softmax.
    const float* kv_w  = (const float*)d_in[3];
    const float* kv_b  = (const float*)d_in[4];
    const float* att_w = (const float*)d_in[5];
    const float* ff1_w = (const float*)d_in[7];
    const float* ff1_b = (const float*)d_in[8];
    const float* ff2_w = (const float*)d_in[9];
    const float* ff2_b = (const float*)d_in[10];
    const float* gn_w  = (const float*)d_in[11];
    const float* gn_b  = (const float*)d_in[12];

    // ws layout (~28.9 MB): c0, c1 ping-pong activations; no live aliasing.
    float* ws  = (float*)d_ws;
    float* c0  = ws;                          // CL fp32 (24,1024,128)
    float* c1  = c0 + (size_t)NELEM;
    float* ak  = c1 + (size_t)NELEM;          // 98304
    float* pstat = ak + 98304;                // 2 sets x 192 (ping-pong)
    unsigned short* W2d  = (unsigned short*)(pstat + 384);   // 1,474,560
    unsigned short* W2kv = W2d + 1474560;                    // 184,320
    // d_out doubles as the fp32 v buffer (dead before the final output write).
    float* v    = (float*)d_out;
    float* outp = (float*)d_out;

    k_prep<<<7248, 256, 0, stream>>>(ff1_w, ff2_w, kv_w, input, W2d, W2kv, c0);

    for (int li = 0; li < 5; li++) {
        float* cin  = (li & 1) ? c1 : c0;
        float* cout = (li & 1) ? c0 : c1;
        float* psC = pstat + (li & 1) * 192;                 // this layer's stats
        const float* psP = li ? pstat + ((li - 1) & 1) * 192 : nullptr;
        const float* gwP = li ? gn_w + (li - 1) * 128 : nullptr;
        const float* gbP = li ? gn_b + (li - 1) * 128 : nullptr;

        // v = grouped conv(GN(cin)) + kv_b ; k = v + pos ; ak = logit conv(k)
        k_kvattn<<<dim3(IMG, 4, 4), 256, 0, stream>>>(
            cin, W2kv + (size_t)li * 36864, kv_b + li * 128, att_w + (size_t)li * 2304,
            psP, gwP, gbP, v, ak, psC);
        // cin = GN(cin) + softmax-weighted sum of v  (= A, in-place elementwise)
        k_wsum<<<1024, 256, 0, stream>>>(ak, v, cin, psP, gwP, gbP);
        // cout = conv(relu(conv(cin,ff1)+b1),ff2)+b2 + cin  (+ GN partial stats)
        k_ffn<<<dim3(IMG, 32), 256, 0, stream>>>(
            cin, W2d + (size_t)(li * 2 + 0) * 147456, ff1_b + li * 128,
            W2d + (size_t)(li * 2 + 1) * 147456, ff2_b + li * 128, cout, psC);
    }
    // final: out = GN(c1) transposed to NCHW (layer 4 wrote cout=c1, stats set 0)
    k_gnlast<<<3072, 256, 0, stream>>>(c1, pstat + 0, gn_w + 4 * 128,
                                       gn_b + 4 * 128, outp);
}

// Round 22
// 421.704 us; speedup vs baseline: 1.0242x; 1.0242x over previous
//
#include <hip/hip_runtime.h>

// B=2, T=12, C=128, H=W=32, heads=4, dh=32, layers=5. fp32 I/O.
// Algebra: key-axis softmax cancels q-conv & att_b; attention weights are
// query-independent (head output broadcast over the 12 frames).
// Round 22 (final): R20 verbatim — best verified configuration (428.0us).
// R21's kv A-reuse remap regressed (431.9: wave-3 idle MFMA slots + longer
// serial chain outweighed the read savings) and is reverted. Session wins
// were all structural memory-op cuts: R3 LDS staging, R9 ff1 A-reuse,
// R19 logit-conv read-halving, R20 kv B-fragment hoist. All scheduling /
// occupancy / latency / I-fetch levers tested null or worse (R10-R17).
#define NELEM 3145728
#define IMG 24
#define CH 128
#define HW 1024

using short8   = __attribute__((ext_vector_type(8))) short;
using ushort4v = __attribute__((ext_vector_type(4))) unsigned short;
using float4v  = __attribute__((ext_vector_type(4))) float;
using float16v = __attribute__((ext_vector_type(16))) float;

__device__ inline unsigned short f2bf(float f){
    union { float f; unsigned u; } c; c.f = f;
    return (unsigned short)((c.u + 0x7FFF + ((c.u >> 16) & 1)) >> 16);
}

// ---------------- fused prep: weight transforms + input transpose ----------------
// Dense W3 layout: short8 idx = ((tap*8 + k16)*2 + kh)*128 + co ; j=ci%8,
// ci = k16*16 + kh*8 + j. KV W3: short8 idx = ((tap*2 + k16)*2 + kh)*128 + co,
// ci_local = k16*16 + kh*8 + j (head = co>>5).
__global__ __launch_bounds__(256) void k_prep(
    const float* __restrict__ ff1w, const float* __restrict__ ff2w,
    const float* __restrict__ kvw, const float* __restrict__ input,
    unsigned short* __restrict__ Wd, unsigned short* __restrict__ Wkv,
    float* __restrict__ cur)
{
    const int t = threadIdx.x;
    __shared__ float tile[32 * 132];
    if (blockIdx.x < 5760) {
        int idx = blockIdx.x * 256 + t;
        int li2 = idx / 147456, r1 = idx - li2 * 147456;
        int j = r1 & 7, co = (r1 >> 3) & 127;
        int kh = (r1 >> 10) & 1, k16 = (r1 >> 11) & 7, tap = r1 >> 14;
        int ci = k16 * 16 + kh * 8 + j;
        const float* base = ((li2 & 1) ? ff2w : ff1w) + (size_t)(li2 >> 1) * 147456;
        Wd[idx] = f2bf(base[(co * 128 + ci) * 9 + tap]);
    } else if (blockIdx.x < 6480) {
        int idx = (blockIdx.x - 5760) * 256 + t;
        int li = idx / 36864, r1 = idx - li * 36864;
        int j = r1 & 7, co = (r1 >> 3) & 127;
        int kh = (r1 >> 10) & 1, k16 = (r1 >> 11) & 1, tap = r1 >> 12;
        int h = co >> 5, colc = co & 31, cil = k16 * 16 + kh * 8 + j;
        Wkv[idx] = f2bf(kvw[((size_t)((li * 4 + h) * 32 + colc) * 32 + cil) * 9 + tap]);
    } else {
        int bb = blockIdx.x - 6480;                  // 24 img x 32 px-tiles
        int img = bb >> 5, px0 = (bb & 31) * 32;
        #pragma unroll
        for (int it = 0; it < 4; it++) {
            int c = it * 32 + (t >> 3), pxq = t & 7;
            float4v val = *(const float4v*)(input + ((size_t)img * 128 + c) * HW + px0 + pxq * 4);
            #pragma unroll
            for (int j = 0; j < 4; j++) tile[(pxq * 4 + j) * 132 + c] = val[j];
        }
        __syncthreads();
        #pragma unroll
        for (int it = 0; it < 4; it++) {
            int px = it * 8 + (t >> 5), cq = t & 31;
            float4v o = *(float4v*)(tile + px * 132 + cq * 4);
            *(float4v*)(cur + ((size_t)img * HW + px0 + px) * 128 + cq * 4) = o;
        }
    }
}

// ---------------- fused kv-conv + attention-logit conv ----------------
// Logit conv (R19): 4 x-adjacent px/thread, ci split 4-ways across waves.
// sxv: row stride 35, plane stride 353. Partials -> sred (aliased over dead
// slab) -> 64-thread tree reduce -> float4 stores.
// kv-conv (R20): B-fragments hoisted out of the f-loop (f-invariant);
// f-loop statically unrolled 3x with wave-uniform f<10 guard.
__global__ __launch_bounds__(256, 2) void k_kvattn(
    const float* __restrict__ cur, const unsigned short* __restrict__ wkv,
    const float* __restrict__ kvb, const float* __restrict__ aw,
    const float* __restrict__ pstatp, const float* __restrict__ gw,
    const float* __restrict__ gb, float* __restrict__ v,
    float* __restrict__ ak, float* __restrict__ pstatz)
{
    const int img = blockIdx.x, h = blockIdx.y, y0 = blockIdx.z * 8;
    const int t = threadIdx.x;
    const int b = img / 12, l = img - b * 12;

    if (blockIdx.x == 0 && blockIdx.y == 0 && blockIdx.z == 0 && t < 192)
        pstatz[t] = 0.f;

    __shared__ float sxv[32 * 353];                            // 45184 B
    __shared__ __align__(16) unsigned short slab[408 * 40];    // 32640 B
    __shared__ float spos[32], sbias[32], sgw[32], sgb[32];

    if (t < 32) {
        int j2 = t & ~1;
        float freq = __expf(-(float)j2 * 0.28782313662425576f);
        float ang = (float)l * freq;
        spos[t] = (t & 1) ? __cosf(ang) : __sinf(ang);
        sbias[t] = kvb[h * 32 + t];
        sgw[t] = gw ? gw[h * 32 + t] : 1.f;
        sgb[t] = gb ? gb[h * 32 + t] : 0.f;
    }
    float mu = 0.f, inv = 1.f;
    if (pstatp) {
        float S = pstatp[(img * 4 + h) * 2], Q = pstatp[(img * 4 + h) * 2 + 1];
        mu = S * (1.f / 32768.f);
        inv = rsqrtf(Q * (1.f / 32768.f) - mu * mu + 1e-5f);
    }
    __syncthreads();

    // stage: 12 rows x 34 cols x 8 float4-groups of the head's 32 ch
    for (int u = t; u < 3264; u += 256) {
        int q = u & 7, p = u >> 3;
        int lr = p / 34, lc = p - lr * 34;
        int yr = y0 - 2 + lr, x = lc - 1;
        float4v val = (float4v){0.f, 0.f, 0.f, 0.f};
        if (yr >= 0 && yr < 32 && x >= 0 && x < 32) {
            val = *(const float4v*)(cur + ((size_t)img * HW + yr * 32 + x) * 128 + h * 32 + q * 4);
            #pragma unroll
            for (int j = 0; j < 4; j++)
                val[j] = (val[j] - mu) * inv * sgw[q * 4 + j] + sgb[q * 4 + j];
        }
        ushort4v o;
        #pragma unroll
        for (int j = 0; j < 4; j++) o[j] = f2bf(val[j]);
        *(ushort4v*)(slab + p * 40 + q * 4) = o;
    }
    __syncthreads();

    const int lane = t & 63, wave = t >> 6;
    const int colx = lane & 31, kh = lane >> 5;
    const short8* w8 = reinterpret_cast<const short8*>(wkv);

    // hoisted f-invariant B fragments: 18 short8 (72 VGPR)
    short8 BV[9][2];
    #pragma unroll
    for (int tap = 0; tap < 9; tap++)
        #pragma unroll
        for (int k16 = 0; k16 < 2; k16++)
            BV[tap][k16] = w8[((tap * 2 + k16) * 2 + kh) * 128 + h * 32 + colx];

    #pragma unroll
    for (int fi = 0; fi < 3; fi++) {
        const int f = wave + fi * 4;
        if (f < 10) {
            float16v acc;
            #pragma unroll
            for (int r = 0; r < 16; r++) acc[r] = 0.f;
            #pragma unroll
            for (int tap = 0; tap < 9; tap++) {
                const int ky = tap / 3, kx = tap - ky * 3;
                #pragma unroll
                for (int k16 = 0; k16 < 2; k16++) {
                    short8 a = *reinterpret_cast<const short8*>(
                        slab + ((f + ky) * 34 + colx + kx) * 40 + k16 * 16 + kh * 8);
                    acc = __builtin_amdgcn_mfma_f32_32x32x16_bf16(
                        a, BV[tap][k16], acc, 0, 0, 0);
                }
            }
            const int yr = y0 - 1 + f;
            const bool rowin = (yr >= 0 && yr < 32);
            const bool vown = rowin && f >= 1 && f <= 8;   // rows this block owns
            const float posci = spos[colx], bb = sbias[colx];
            float* vrow = v + ((size_t)img * HW + yr * 32) * 128 + h * 32 + colx;
            #pragma unroll
            for (int r = 0; r < 16; r++) {
                int x2 = (r & 3) + 8 * (r >> 2) + 4 * kh;
                float val = rowin ? acc[r] + bb : 0.f;
                if (vown) vrow[(size_t)x2 * 128] = val;
                sxv[colx * 353 + f * 35 + x2 + 1] = rowin ? val + posci : 0.f;
            }
        }
    }
    // zero padded border cols (0 and 33) of all 10 rows
    for (int u = t; u < 640; u += 256) {
        int ci = u & 31, r2 = u >> 5;
        sxv[ci * 353 + (r2 >> 1) * 35 + ((r2 & 1) ? 33 : 0)] = 0.f;
    }
    __syncthreads();

    // logit conv: thread (g=wave, u=lane) computes 4 px (row rr, cols x0..x0+3)
    // over its 8-ci octet: 6-float row windows feed 12 fmaf each (ky).
    const int g = wave, u2 = lane;
    const int rr = u2 >> 3, x0 = (u2 & 7) * 4;
    const float* wbg = aw + (h * 64 + 32) * 9 + g * 72;   // K-half, ci octet g
    float4v pacc = (float4v){0.f, 0.f, 0.f, 0.f};
    #pragma unroll
    for (int ci = 0; ci < 8; ci++) {
        const float* sp = sxv + (g * 8 + ci) * 353 + rr * 35 + x0;
        const float* wp = wbg + ci * 9;
        #pragma unroll
        for (int ky = 0; ky < 3; ky++) {
            float f0 = sp[ky*35+0], f1 = sp[ky*35+1], f2 = sp[ky*35+2];
            float f3 = sp[ky*35+3], f4 = sp[ky*35+4], f5 = sp[ky*35+5];
            float w0 = wp[ky*3+0], w1 = wp[ky*3+1], w2f = wp[ky*3+2];
            pacc[0] = fmaf(f2, w2f, fmaf(f1, w1, fmaf(f0, w0, pacc[0])));
            pacc[1] = fmaf(f3, w2f, fmaf(f2, w1, fmaf(f1, w0, pacc[1])));
            pacc[2] = fmaf(f4, w2f, fmaf(f3, w1, fmaf(f2, w0, pacc[2])));
            pacc[3] = fmaf(f5, w2f, fmaf(f4, w1, fmaf(f3, w0, pacc[3])));
        }
    }
    // reduce across the 4 ci-octets via LDS (sred aliased over dead slab)
    float4v* sred = reinterpret_cast<float4v*>(slab);
    sred[g * 64 + u2] = pacc;
    __syncthreads();
    if (t < 64) {
        float4v s = sred[t];
        #pragma unroll
        for (int gg = 1; gg < 4; gg++) {
            float4v o = sred[gg * 64 + t];
            #pragma unroll
            for (int j = 0; j < 4; j++) s[j] += o[j];
        }
        *reinterpret_cast<float4v*>(ak + ((size_t)(b * 4 + h) * 12 + l) * HW
                                    + (y0 + (t >> 3)) * 32 + (t & 7) * 4) = s;
    }
}

// ---------------- fused FFN: cout = conv(relu(conv(cin,ff1)+b1),ff2)+b2+cin ----------------
// grid (24 img, 32 y). Block 256 = 4 waves, wave w owns co group w*32..+32.
// LDS aliased (46240 B, 3 blocks/CU):
//   phase A: s1 = 5 padded rows x 34 x 128ch bf16 of cin (stride 136).
//   phase B (after ff1's reads drain): s2 = 3 f1 rows (stride 136) at base.
// ff1 A-reuse (R9): one ds_read feeds up to 3 MFMAs. B dbuf as R11.
// Direct-from-accumulator epilogue (R13): ff2 D-frag = 2x128B contiguous
// global segments per reg; residual cin prefetched into regs after bar3;
// GN stats full-wave butterfly (group == wave id), 2 atomics/wave.
__global__ __launch_bounds__(256, 2) void k_ffn(
    const float* __restrict__ cin, const unsigned short* __restrict__ w1,
    const float* __restrict__ b1, const unsigned short* __restrict__ w2,
    const float* __restrict__ b2, float* __restrict__ cout,
    float* __restrict__ pstat)
{
    const int img = blockIdx.x, y = blockIdx.y;
    const int t = threadIdx.x;
    const int wave = t >> 6, lane = t & 63;
    const int colx = lane & 31, kh = lane >> 5;
    const int cog = wave * 32;

    __shared__ __align__(16) char smem[46240];
    unsigned short* s1 = (unsigned short*)smem;          // 170*136 shorts
    unsigned short* s2 = (unsigned short*)smem;          // 102*136 shorts (aliased)

    // stage s1: rows y-2..y+2, cols -1..32, 128 ch (border-checked)
    for (int u = t; u < 5440; u += 256) {
        int q = u & 31, p = u >> 5;
        int lr = p / 34, lc = p - lr * 34;
        int yr = y - 2 + lr, x = lc - 1;
        float4v val = (float4v){0.f, 0.f, 0.f, 0.f};
        if (yr >= 0 && yr < 32 && x >= 0 && x < 32)
            val = *(const float4v*)(cin + ((size_t)img * HW + yr * 32 + x) * 128 + q * 4);
        ushort4v o;
        #pragma unroll
        for (int j = 0; j < 4; j++) o[j] = f2bf(val[j]);
        *(ushort4v*)(s1 + p * 136 + q * 4) = o;
    }

    const short8* w8a = reinterpret_cast<const short8*>(w1);
    const short8* w8b = reinterpret_cast<const short8*>(w2);
    const int bl = kh * 128 + cog + colx;       // per-lane short8 index into W3

    float16v acc[3];
    #pragma unroll
    for (int f = 0; f < 3; f++)
        #pragma unroll
        for (int r = 0; r < 16; r++) acc[f][r] = 0.f;

    // ff1 B double buffer: prefetch k16=0's 9 taps (overlaps stage + barrier)
    short8 B9[2][9];
    #pragma unroll
    for (int tap = 0; tap < 9; tap++)
        B9[0][tap] = w8a[(tap * 8 + 0) * 256 + bl];

    __syncthreads();                            // bar1: s1 staged

    // ff1: A-reuse across output rows. For (ar,kx,k16): one ds_read feeds
    // acc[ar-ky] for all valid ky. 15 reads + 27 MFMA per k16; next k16's
    // 9 B-loads issue before the MFMA burst (latency hidden under compute).
    #pragma unroll
    for (int k16 = 0; k16 < 8; k16++) {
        if (k16 + 1 < 8) {
            #pragma unroll
            for (int tap = 0; tap < 9; tap++)
                B9[(k16 + 1) & 1][tap] = w8a[(tap * 8 + k16 + 1) * 256 + bl];
        }
        #pragma unroll
        for (int ar = 0; ar < 5; ar++) {
            #pragma unroll
            for (int kx = 0; kx < 3; kx++) {
                short8 a = *reinterpret_cast<const short8*>(
                    s1 + (ar * 34 + kx + colx) * 136 + kh * 8 + k16 * 16);
                #pragma unroll
                for (int ky = 0; ky < 3; ky++) {
                    const int f = ar - ky;
                    if (f >= 0 && f < 3)
                        acc[f] = __builtin_amdgcn_mfma_f32_32x32x16_bf16(
                            a, B9[k16 & 1][ky * 3 + kx], acc[f], 0, 0, 0);
                }
            }
        }
    }

    // ff2 B double buffer
    short8 bfr[2][8];
    auto loadB2 = [&](int tap, int buf){
        #pragma unroll
        for (int k16 = 0; k16 < 8; k16++)
            bfr[buf][k16] = w8b[(tap * 8 + k16) * 256 + bl];
    };
    loadB2(0, 0);                               // overlap with barrier + s2 writes
    __syncthreads();                            // bar2: all s1 reads done

    // write f1 rows into s2 (aliased over s1): relu + bias; zero rows outside
    {
        const int co = cog + colx;
        const float bb1 = b1[co];
        #pragma unroll
        for (int f = 0; f < 3; f++) {
            const bool rowin = (y - 1 + f >= 0) && (y - 1 + f < 32);
            #pragma unroll
            for (int r = 0; r < 16; r++) {
                int x2 = (r & 3) + 8 * (r >> 2) + 4 * kh;
                float val = rowin ? fmaxf(acc[f][r] + bb1, 0.f) : 0.f;
                s2[(f * 34 + x2 + 1) * 136 + co] = f2bf(val);
            }
        }
    }
    // zero s2 border cols (x=0 and x=33) of all 3 rows
    for (int u = t; u < 768; u += 256) {
        int c = u & 127, rr = u >> 7;            // rr 0..5
        s2[((rr >> 1) * 34 + ((rr & 1) ? 33 : 0)) * 136 + c] = 0;
    }
    __syncthreads();                            // bar3: s2 ready

    // prefetch residual cin for this wave's 16 output elements (hidden
    // under ff2's MFMAs; 2x128B contiguous segments per r across the wave)
    const int co = cog + colx;
    float res[16];
    #pragma unroll
    for (int r = 0; r < 16; r++) {
        int x2 = (r & 3) + 8 * (r >> 2) + 4 * kh;
        res[r] = cin[((size_t)img * HW + y * 32 + x2) * 128 + co];
    }

    // ff2: row y; prefetch tap+1's B under tap's MFMAs
    float16v a2;
    #pragma unroll
    for (int r = 0; r < 16; r++) a2[r] = 0.f;
    #pragma unroll
    for (int tap = 0; tap < 9; tap++) {
        if (tap + 1 < 9) loadB2(tap + 1, (tap + 1) & 1);
        const int ky = tap / 3, kx = tap - ky * 3;
        #pragma unroll
        for (int k16 = 0; k16 < 8; k16++) {
            short8 a = *reinterpret_cast<const short8*>(
                s2 + (ky * 34 + kx + colx) * 136 + kh * 8 + k16 * 16);
            a2 = __builtin_amdgcn_mfma_f32_32x32x16_bf16(a, bfr[tap & 1][k16], a2, 0, 0, 0);
        }
    }

    // direct epilogue: bias + residual + store from accumulator + GN stats
    const float bb2 = b2[co];
    float ps1 = 0.f, ps2 = 0.f;
    #pragma unroll
    for (int r = 0; r < 16; r++) {
        int x2 = (r & 3) + 8 * (r >> 2) + 4 * kh;
        float val = a2[r] + bb2 + res[r];
        cout[((size_t)img * HW + y * 32 + x2) * 128 + co] = val;
        ps1 += val; ps2 += val * val;
    }
    // all 64 lanes share channel-group == wave id: full butterfly reduce
    #pragma unroll
    for (int o = 32; o > 0; o >>= 1) {
        ps1 += __shfl_xor(ps1, o); ps2 += __shfl_xor(ps2, o);
    }
    if (lane == 0) {
        atomicAdd(&pstat[(img * 4 + wave) * 2], ps1);
        atomicAdd(&pstat[(img * 4 + wave) * 2 + 1], ps2);
    }
}

// ---------------- fused softmax + weighted sum + GN-on-read residual ----------------
// one channel per thread: 262144 threads, 1024 blocks (4/CU), all coalesced.
__global__ __launch_bounds__(256) void k_wsum(const float* __restrict__ ak,
    const float* __restrict__ v, float* __restrict__ cur,
    const float* __restrict__ pstatp, const float* __restrict__ gw,
    const float* __restrict__ gb)
{
    int gid = blockIdx.x * 256 + threadIdx.x;   // 2*1024*128
    int c = gid & 127, px = (gid >> 7) & 1023, b = gid >> 17;
    int h = c >> 5;
    const float* wp = ak + ((size_t)(b * 4 + h) * 12) * HW + px;
    float a[12], m = -1e30f;
    #pragma unroll
    for (int l = 0; l < 12; l++) { a[l] = wp[l * HW]; m = fmaxf(m, a[l]); }
    float ssum = 0.f;
    #pragma unroll
    for (int l = 0; l < 12; l++) { a[l] = __expf(a[l] - m); ssum += a[l]; }
    float invs = 1.f / ssum;
    const float* vp = v + ((size_t)(b * 12) * HW + px) * 128 + c;
    float s = 0.f;
    #pragma unroll
    for (int l = 0; l < 12; l++) s += a[l] * vp[(size_t)l * HW * 128];
    s *= invs;
    float gwv = gw ? gw[c] : 1.f, gbv = gb ? gb[c] : 0.f;
    float* cp = cur + ((size_t)(b * 12) * HW + px) * 128 + c;
    #pragma unroll
    for (int l = 0; l < 12; l++) {
        int img = b * 12 + l;
        float mu = 0.f, inv = 1.f;
        if (pstatp) {
            float S = pstatp[(img * 4 + h) * 2], Q = pstatp[(img * 4 + h) * 2 + 1];
            mu = S * (1.f / 32768.f);
            inv = rsqrtf(Q * (1.f / 32768.f) - mu * mu + 1e-5f);
        }
        float cv = cp[(size_t)l * HW * 128];
        cp[(size_t)l * HW * 128] = (cv - mu) * inv * gwv + gbv + s;
    }
}

// ---------------- final GroupNorm + NCHW transpose ----------------
__global__ __launch_bounds__(256) void k_gnlast(const float* __restrict__ y,
    const float* __restrict__ pstat, const float* __restrict__ gw,
    const float* __restrict__ gb, float* __restrict__ outp)
{
    int gid = blockIdx.x * 256 + threadIdx.x;   // 24*1024*32
    int px4 = (gid & 255) * 4, c = (gid >> 8) & 127, img = gid >> 15;
    int g = c >> 5;
    float S = pstat[(img * 4 + g) * 2], Q = pstat[(img * 4 + g) * 2 + 1];
    float mu = S * (1.f / 32768.f);
    float inv = rsqrtf(Q * (1.f / 32768.f) - mu * mu + 1e-5f);
    float gg = gw[c], bb = gb[c];
    float4v o;
    #pragma unroll
    for (int j = 0; j < 4; j++) {
        float val = y[((size_t)img * HW + px4 + j) * 128 + c];
        o[j] = (val - mu) * inv * gg + bb;
    }
    *(float4v*)(outp + ((size_t)img * 128 + c) * HW + px4) = o;
}

extern "C" void kernel_launch(void* const* d_in, const int* in_sizes, int n_in,
                              void* d_out, int out_size, void* d_ws, size_t ws_size,
                              hipStream_t stream)
{
    const float* input = (const float*)d_in[0];
    // d_in[1] q_w, d_in[2] q_b, d_in[6] att_b cancel in key-axis softmax.
    const float* kv_w  = (const float*)d_in[3];
    const float* kv_b  = (const float*)d_in[4];
    const float* att_w = (const float*)d_in[5];
    const float* ff1_w = (const float*)d_in[7];
    const float* ff1_b = (const float*)d_in[8];
    const float* ff2_w = (const float*)d_in[9];
    const float* ff2_b = (const float*)d_in[10];
    const float* gn_w  = (const float*)d_in[11];
    const float* gn_b  = (const float*)d_in[12];

    // ws layout (~28.9 MB): c0, c1 ping-pong activations; no live aliasing.
    float* ws  = (float*)d_ws;
    float* c0  = ws;                          // CL fp32 (24,1024,128)
    float* c1  = c0 + (size_t)NELEM;
    float* ak  = c1 + (size_t)NELEM;          // 98304
    float* pstat = ak + 98304;                // 2 sets x 192 (ping-pong)
    unsigned short* W2d  = (unsigned short*)(pstat + 384);   // 1,474,560
    unsigned short* W2kv = W2d + 1474560;                    // 184,320
    // d_out doubles as the fp32 v buffer (dead before the final output write).
    float* v    = (float*)d_out;
    float* outp = (float*)d_out;

    k_prep<<<7248, 256, 0, stream>>>(ff1_w, ff2_w, kv_w, input, W2d, W2kv, c0);

    for (int li = 0; li < 5; li++) {
        float* cin  = (li & 1) ? c1 : c0;
        float* cout = (li & 1) ? c0 : c1;
        float* psC = pstat + (li & 1) * 192;                 // this layer's stats
        const float* psP = li ? pstat + ((li - 1) & 1) * 192 : nullptr;
        const float* gwP = li ? gn_w + (li - 1) * 128 : nullptr;
        const float* gbP = li ? gn_b + (li - 1) * 128 : nullptr;

        // v = grouped conv(GN(cin)) + kv_b ; k = v + pos ; ak = logit conv(k)
        k_kvattn<<<dim3(IMG, 4, 4), 256, 0, stream>>>(
            cin, W2kv + (size_t)li * 36864, kv_b + li * 128, att_w + (size_t)li * 2304,
            psP, gwP, gbP, v, ak, psC);
        // cin = GN(cin) + softmax-weighted sum of v  (= A, in-place elementwise)
        k_wsum<<<1024, 256, 0, stream>>>(ak, v, cin, psP, gwP, gbP);
        // cout = conv(relu(conv(cin,ff1)+b1),ff2)+b2 + cin  (+ GN partial stats)
        k_ffn<<<dim3(IMG, 32), 256, 0, stream>>>(
            cin, W2d + (size_t)(li * 2 + 0) * 147456, ff1_b + li * 128,
            W2d + (size_t)(li * 2 + 1) * 147456, ff2_b + li * 128, cout, psC);
    }
    // final: out = GN(c1) transposed to NCHW (layer 4 wrote cout=c1, stats set 0)
    k_gnlast<<<3072, 256, 0, stream>>>(c1, pstat + 0, gn_w + 4 * 128,
                                       gn_b + 4 * 128, outp);
}